// Round 2
// baseline (252.833 us; speedup 1.0000x reference)
//
#include <hip/hip_runtime.h>

// x: (B=32, H=256, W=256, C=16) float32, row-major.
// p[h][w] = mean over (b, c) of x[b][h][w][c]  (512 values per (h,w))
// out = p >= 0.25 ? x*0.25/p : 1 - (0.75/(1-p))*(1-x)  ==  a*x + d
//
// Round 4: UN-FUSE. Round-3 evidence: fused reduce+apply is structurally
// latency-bound — every block must drain vmcnt(0) at a barrier before it
// can store, and occupancy fell to 33% (32 KiB LDS rounds up in the
// allocator), so the drain is unhidden: VALUBusy 4.5%, HBM 26%, 92 us.
// Split into two barrier-free, LDS-free streaming kernels:
//   1) reduce_kernel: x -> ad[hw]=(a,d) table (512 KiB in d_ws).
//      8 threads per (h,w): 4 c-quads x 2 b-halves; 16 independent
//      dwordx4 loads/thread (16-deep MLP), shfl_xor(1,2,4) reduce.
//      No LDS, low VGPR -> near-full occupancy. ~134 MB read.
//   2) apply_kernel: out = a*x + d, grid-stride. Grid span (2048 blk x
//      256 thr = 524,288 float4) == exactly 2 batches, so each thread's
//      in-batch offset — hence its (a,d) — is LOOP-INVARIANT: one 8 B
//      table load, then 16 x {load f4, fma, nontemporal store}.
//      x reads hit L3 (kernel 1 just streamed x through it); NT stores
//      keep the write stream from evicting x.

#define ALPHA 0.25f

typedef float v4f __attribute__((ext_vector_type(4)));

// ---------------- kernel 1: reduce x over (b,c), emit (a,d) ----------------
__global__ __launch_bounds__(256) void reduce_kernel(
    const float* __restrict__ x, float2* __restrict__ ad) {
  constexpr long ELEM_PER_B = 1L << 20;  // 256*256*16 floats per batch

  const int t  = blockIdx.x * 256 + threadIdx.x;  // 0 .. 524287
  const int hw = t >> 3;                          // 8 threads per (h,w)
  const int cq = t & 3;                           // c-quad: floats [4cq,4cq+4)
  const int bh = (t >> 2) & 1;                    // b-half: b in [16bh,16bh+16)

  const float* base = x + (long)hw * 16 + cq * 4 + (long)bh * 16 * ELEM_PER_B;

  // 16 independent dwordx4 loads -> deep MLP, no barriers.
  float s = 0.0f;
#pragma unroll
  for (int bi = 0; bi < 16; ++bi) {
    const float4 v = *(const float4*)(base + (long)bi * ELEM_PER_B);
    s += (v.x + v.y) + (v.z + v.w);
  }
  // lanes differing in bits {0,1} = c-quads, bit {2} = b-half
  s += __shfl_xor(s, 1);
  s += __shfl_xor(s, 2);   // all 16 c
  s += __shfl_xor(s, 4);   // all 32 b
  const float p = s * (1.0f / 512.0f);

  float a, d;
  if (p >= ALPHA) {
    a = ALPHA / p;
    d = 0.0f;
  } else {
    const float beta = (1.0f - ALPHA) / (1.0f - p);
    a = beta;
    d = 1.0f - beta;
  }
  if ((t & 7) == 0) ad[hw] = make_float2(a, d);  // 8 B per hw, contiguous
}

// ---------------- kernel 2: out = a*x + d, pure streaming ----------------
__global__ __launch_bounds__(256) void apply_kernel(
    const float* __restrict__ x, const float2* __restrict__ ad,
    float* __restrict__ out) {
  constexpr long STRIDE_F4 = 2048L * 256;  // grid span = 524,288 f4 = 2 batches
  constexpr int F4_PER_B_MASK = (1 << 18) - 1;  // 262,144 f4 per batch

  const long i = (long)blockIdx.x * 256 + threadIdx.x;  // 0 .. 524287
  const int inb = (int)i & F4_PER_B_MASK;  // in-batch f4 index (loop-invariant)
  const float2 adv = ad[inb >> 2];         // (a,d) for this thread, ALL iters

  const float4* __restrict__ xp = (const float4*)x + i;
  v4f* __restrict__ op = (v4f*)out + i;

#pragma unroll
  for (int j = 0; j < 16; ++j) {
    const float4 v = xp[j * STRIDE_F4];
    v4f r;
    r.x = fmaf(adv.x, v.x, adv.y);
    r.y = fmaf(adv.x, v.y, adv.y);
    r.z = fmaf(adv.x, v.z, adv.y);
    r.w = fmaf(adv.x, v.w, adv.y);
    __builtin_nontemporal_store(r, op + j * STRIDE_F4);
  }
}

extern "C" void kernel_launch(void* const* d_in, const int* in_sizes, int n_in,
                              void* d_out, int out_size, void* d_ws, size_t ws_size,
                              hipStream_t stream) {
  const float* x = (const float*)d_in[0];
  float* out = (float*)d_out;
  float2* ad = (float2*)d_ws;  // 65536 * 8 B = 512 KiB workspace

  reduce_kernel<<<dim3(2048), dim3(256), 0, stream>>>(x, ad);
  apply_kernel<<<dim3(2048), dim3(256), 0, stream>>>(x, ad, out);
}

// Round 3
// 243.734 us; speedup vs baseline: 1.0373x; 1.0373x over previous
//
#include <hip/hip_runtime.h>

// x: (B=32, H=256, W=256, C=16) float32, row-major.
// p[h][w] = mean over (b, c) of x[b][h][w][c]  (512 values per (h,w))
// out = p >= 0.25 ? x*0.25/p : 1 - (0.75/(1-p))*(1-x)  ==  a*x + d
//
// Round 5: BARRIER-FREE FUSION. Evidence trail:
//  - r0 (fused, LDS cross-wave reduce): 85 us. VGPR=28 => the 8 loads were
//    SUNK past __syncthreads (asm pin without "memory" doesn't order loads)
//    => x read twice, 2nd read latency-exposed. The barrier is the enabler
//    of that restructuring AND the structural stall (vmcnt(0) drain).
//  - r1 (LDS-staged): 92 us, occupancy 33% — drain unhidden.
//  - r2 (split reduce/apply): ~100 us combined — 2nd full x read costs more
//    than un-fusing saves. BUT: harness fill kernels prove 6.7 TB/s at 9.5%
//    occupancy with 8 VGPRs — streaming needs no occupancy, just no syncs.
// Fix: the (b,c)-reduction fits in 8 LANES (4 c-quads x 2 b-halves,
// shfl_xor 1,2,4) — no LDS, no barrier anywhere. Each thread: 16
// independent float4 loads (one per batch, 4 MB stride), sum, 3 shfls,
// a,d, then FMA+NT-store from the SAME registers. Loads cannot sink past
// the shfls (s depends on all of them), so single-read is guaranteed by
// dataflow. __launch_bounds__(256,4) = 128 VGPR budget so the 64 data
// regs stay live instead of being remat'd for occupancy (r0 failure mode).
// Traffic: 134 MB read + 134 MB write = 268 MB ~= 40-55 us at 5-6.7 TB/s.

#define ALPHA 0.25f

typedef float v4f __attribute__((ext_vector_type(4)));

__global__ __launch_bounds__(256, 4) void fused_kernel(
    const float* __restrict__ x, float* __restrict__ out) {
  constexpr long ELEM_PER_B = 1L << 20;  // 256*256*16 floats per batch

  const int t  = blockIdx.x * 256 + threadIdx.x;  // 0 .. 524287
  const int hw = t >> 3;                          // 8 threads per (h,w)
  const int cq = t & 3;                           // c-quad: floats [4cq,4cq+4)
  const int bh = (t >> 2) & 1;                    // b-half: b in [16bh,16bh+16)

  const long off = (long)hw * 16 + cq * 4 + (long)bh * 16 * ELEM_PER_B;
  const float* __restrict__ xp = x + off;

  // 16 independent dwordx4 loads (16-deep MLP), summed as they land.
  float4 v[16];
  float s = 0.0f;
#pragma unroll
  for (int bi = 0; bi < 16; ++bi) {
    v[bi] = *(const float4*)(xp + (long)bi * ELEM_PER_B);
    s += (v[bi].x + v[bi].y) + (v[bi].z + v[bi].w);
  }
  // Belt-and-suspenders: make v[] opaque so regalloc can't remat the loads
  // for the apply phase. (Loads can't sink below here anyway: s needs them.)
#pragma unroll
  for (int bi = 0; bi < 16; ++bi) {
    asm volatile("" : "+v"(v[bi].x), "+v"(v[bi].y), "+v"(v[bi].z),
                      "+v"(v[bi].w));
  }

  // lanes differing in bits {0,1} = c-quads, bit {2} = b-half
  s += __shfl_xor(s, 1);
  s += __shfl_xor(s, 2);   // all 16 c
  s += __shfl_xor(s, 4);   // all 32 b
  const float p = s * (1.0f / 512.0f);

  float a, d;
  if (p >= ALPHA) {
    a = ALPHA / p;
    d = 0.0f;
  } else {
    const float beta = (1.0f - ALPHA) / (1.0f - p);
    a = beta;
    d = 1.0f - beta;
  }

  // Apply to the registers we already hold; NT store (out never re-read).
  float* __restrict__ op = out + off;
#pragma unroll
  for (int bi = 0; bi < 16; ++bi) {
    v4f r;
    r.x = fmaf(a, v[bi].x, d);
    r.y = fmaf(a, v[bi].y, d);
    r.z = fmaf(a, v[bi].z, d);
    r.w = fmaf(a, v[bi].w, d);
    __builtin_nontemporal_store(r, (v4f*)(op + (long)bi * ELEM_PER_B));
  }
}

extern "C" void kernel_launch(void* const* d_in, const int* in_sizes, int n_in,
                              void* d_out, int out_size, void* d_ws, size_t ws_size,
                              hipStream_t stream) {
  const float* x = (const float*)d_in[0];
  float* out = (float*)d_out;
  // 65536 (h,w) positions * 8 threads = 524288 threads = 2048 blocks
  fused_kernel<<<dim3(2048), dim3(256), 0, stream>>>(x, out);
}

// Round 4
// 236.978 us; speedup vs baseline: 1.0669x; 1.0285x over previous
//
#include <hip/hip_runtime.h>

// x: (B=32, H=256, W=256, C=16) float32, row-major.
// p[h][w] = mean over (b, c) of x[b][h][w][c]  (512 values per (h,w))
// out = p >= 0.25 ? x*0.25/p : 1 - (0.75/(1-p))*(1-x)  ==  a*x + d
//
// Round 6: KILL THE REMAT. Evidence trail:
//  - r5: VGPR=44 < 64 needed for v[16] => compiler rematerialized the
//    global loads to feed the pins (legal: pin input is just "the value of
//    v[bi]", recomputable by reloading const __restrict__ x). x read twice;
//    every variant so far converges at ~4.6 TB/s of COMBINED traffic
//    (402 MB incl. the duplicate read). Fill kernels: 6.7 TB/s pure-write,
//    so ~4.6-5 TB/s is the mixed R/W stream ceiling. Only lever left:
//    cut logical traffic 402 -> 268 MB by making the reload ILLEGAL.
// Two changes make remat illegal:
//  1. x is passed WITHOUT __restrict__ -> stores to out may alias x, so a
//     post-store... more importantly:
//  2. every pin carries a "memory" clobber -> the asm may have modified x,
//     so reloading after the pin is no longer provably value-preserving.
//     Loads also cannot sink below the first clobber.
// Plus: 16 threads per (h,w) (4 c-quads x 4 b-quarters, shfl_xor 1,2,4,8)
// so only 8 float4 = 32 data VGPRs must stay live -> cheap for regalloc,
// same aggregate MLP as r5 (2x threads x 8-deep).
// Traffic: 134 MB read (once!) + 134 MB write = 268 MB ~= 55-65 us at the
// observed mixed-stream rate.

#define ALPHA 0.25f

typedef float v4f __attribute__((ext_vector_type(4)));

__global__ __launch_bounds__(256) void fused_kernel(
    const float* x,               // NO __restrict__ — see header comment
    float* __restrict__ out) {
  constexpr long ELEM_PER_B = 1L << 20;  // 256*256*16 floats per batch

  const int t  = blockIdx.x * 256 + threadIdx.x;  // 0 .. 1048575
  const int hw = t >> 4;                          // 16 threads per (h,w)
  const int cq = t & 3;                           // c-quad: floats [4cq,4cq+4)
  const int bq = (t >> 2) & 3;                    // batches [8bq, 8bq+8)

  const long off = (long)hw * 16 + cq * 4 + (long)bq * 8 * ELEM_PER_B;
  const float* xp = x + off;

  // 8 independent dwordx4 loads (8-deep MLP per thread, 2x threads vs r5).
  float4 v[8];
  float s = 0.0f;
#pragma unroll
  for (int bi = 0; bi < 8; ++bi) {
    v[bi] = *(const float4*)(xp + (long)bi * ELEM_PER_B);
    s += (v[bi].x + v[bi].y) + (v[bi].z + v[bi].w);
  }

  // Pin with "memory" clobber: after this, reloading x to recreate v[] is
  // ILLEGAL (the asm may have written memory; x is not restrict-qualified).
  // The 32 data VGPRs must stay live into the apply phase.
#pragma unroll
  for (int bi = 0; bi < 8; ++bi) {
    asm volatile("" : "+v"(v[bi].x), "+v"(v[bi].y), "+v"(v[bi].z),
                      "+v"(v[bi].w) :: "memory");
  }

  // lanes differing in bits {0,1} = c-quads, bits {2,3} = batch-quarters
  s += __shfl_xor(s, 1);
  s += __shfl_xor(s, 2);   // all 16 c
  s += __shfl_xor(s, 4);
  s += __shfl_xor(s, 8);   // all 32 b
  const float p = s * (1.0f / 512.0f);

  float a, d;
  if (p >= ALPHA) {
    a = ALPHA / p;
    d = 0.0f;
  } else {
    const float beta = (1.0f - ALPHA) / (1.0f - p);
    a = beta;
    d = 1.0f - beta;
  }

  // Apply to the registers we hold; NT store (out never re-read).
  float* op = out + off;
#pragma unroll
  for (int bi = 0; bi < 8; ++bi) {
    v4f r;
    r.x = fmaf(a, v[bi].x, d);
    r.y = fmaf(a, v[bi].y, d);
    r.z = fmaf(a, v[bi].z, d);
    r.w = fmaf(a, v[bi].w, d);
    __builtin_nontemporal_store(r, (v4f*)(op + (long)bi * ELEM_PER_B));
  }
}

extern "C" void kernel_launch(void* const* d_in, const int* in_sizes, int n_in,
                              void* d_out, int out_size, void* d_ws, size_t ws_size,
                              hipStream_t stream) {
  const float* x = (const float*)d_in[0];
  float* out = (float*)d_out;
  // 65536 (h,w) positions * 16 threads = 1,048,576 threads = 4096 blocks
  fused_kernel<<<dim3(4096), dim3(256), 0, stream>>>(x, out);
}